// Round 1
// baseline (606.113 us; speedup 1.0000x reference)
//
#include <hip/hip_runtime.h>
#include <math.h>

#define D 128

// One block per triple b. Threads 0..127 handle Pe rows (dot with x=h-t),
// threads 128..255 handle Pr rows (dot with r). Then y = pe_row + pr_row,
// block-reduce sum(y^2), out[b] = sqrt.
__global__ __launch_bounds__(256) void transo_kernel(
    const int* __restrict__ heads,
    const int* __restrict__ relations,
    const int* __restrict__ tails,
    const int* __restrict__ etypes,
    const int* __restrict__ rtypes,
    const float* __restrict__ entity_emb,
    const float* __restrict__ relation_emb,
    const float* __restrict__ eproj,
    const float* __restrict__ rproj,
    float* __restrict__ out)
{
    const int b   = blockIdx.x;
    const int tid = threadIdx.x;

    __shared__ __align__(16) float x[D];    // h - t
    __shared__ __align__(16) float rv[D];   // r
    __shared__ float y[2 * D];              // per-row partial dots
    __shared__ float partial[4];

    const int h_idx = heads[b];
    const int t_idx = tails[b];
    const int r_idx = relations[b];
    const int et    = etypes[b];
    const int rt    = rtypes[b];

    if (tid < D) {
        x[tid]  = entity_emb[(size_t)h_idx * D + tid]
                - entity_emb[(size_t)t_idx * D + tid];
        rv[tid] = relation_emb[(size_t)r_idx * D + tid];
    }
    __syncthreads();

    const int row = tid & (D - 1);
    const float* P = (tid < D)
        ? (eproj + (size_t)et * D * D + (size_t)row * D)
        : (rproj + (size_t)rt * D * D + (size_t)row * D);
    const float* v = (tid < D) ? x : rv;

    const float4* P4 = (const float4*)P;
    const float4* v4 = (const float4*)v;

    float acc = 0.f;
    #pragma unroll
    for (int k = 0; k < D / 4; ++k) {
        float4 p  = P4[k];
        float4 vv = v4[k];   // LDS broadcast (same addr across lanes)
        acc += p.x * vv.x + p.y * vv.y + p.z * vv.z + p.w * vv.w;
    }
    y[tid] = acc;
    __syncthreads();

    // combine Pe and Pr contributions, square, reduce
    float ss = 0.f;
    if (tid < D) {
        float dd = y[tid] + y[tid + D];
        ss = dd * dd;
    }
    // wave64 butterfly reduce (waves 2,3 contribute zeros — harmless)
    #pragma unroll
    for (int off = 32; off > 0; off >>= 1)
        ss += __shfl_down(ss, off, 64);
    if ((tid & 63) == 0) partial[tid >> 6] = ss;
    __syncthreads();

    if (tid == 0) {
        out[b] = sqrtf(partial[0] + partial[1]);
    }
}

extern "C" void kernel_launch(void* const* d_in, const int* in_sizes, int n_in,
                              void* d_out, int out_size, void* d_ws, size_t ws_size,
                              hipStream_t stream) {
    const int*   heads     = (const int*)d_in[0];
    const int*   relations = (const int*)d_in[1];
    const int*   tails     = (const int*)d_in[2];
    const int*   etypes    = (const int*)d_in[3];
    const int*   rtypes    = (const int*)d_in[4];
    const float* eemb      = (const float*)d_in[5];
    const float* remb      = (const float*)d_in[6];
    const float* eproj     = (const float*)d_in[7];
    const float* rproj     = (const float*)d_in[8];
    float* out = (float*)d_out;

    const int B = in_sizes[0];   // 16384

    transo_kernel<<<B, 256, 0, stream>>>(heads, relations, tails, etypes, rtypes,
                                         eemb, remb, eproj, rproj, out);
}

// Round 2
// 483.670 us; speedup vs baseline: 1.2532x; 1.2532x over previous
//
#include <hip/hip_runtime.h>
#include <math.h>

#define D 128
#define NTE 100
#define NTR 50
#define MTILE 64
#define KC 32

// ---- workspace layout (int words) ----
#define W_CNT_E   0        // 128
#define W_CNT_R   128      // 64
#define W_RUN_E   192      // 128
#define W_RUN_R   320      // 64
#define W_OFF_E   384      // 128
#define W_OFF_R   512      // 64
#define W_NE      576
#define W_NR      577
#define W_CHP0_E  640      // 512
#define W_CHN_E   1152     // 512
#define W_CHTT_E  1664     // 512
#define W_CHP0_R  2176     // 512
#define W_CHN_R   2688     // 512
#define W_CHTT_R  3200     // 512
#define W_SRT_E   3712             // B
// INV_E = 3712+B, SRT_R = 3712+2B, INV_R = 3712+3B
#define W_Y_F32   69376            // float offset, 16B-aligned; B*128 floats

__global__ __launch_bounds__(256) void zero_kernel(int* ws) {
    int tid = threadIdx.x;
    if (tid < 192) ws[tid] = 0;   // cnt_e[128] + cnt_r[64]
}

__global__ __launch_bounds__(256) void count_kernel(
    const int* __restrict__ etypes, const int* __restrict__ rtypes,
    int* ws, int B)
{
    for (int b = blockIdx.x * blockDim.x + threadIdx.x; b < B;
         b += gridDim.x * blockDim.x) {
        atomicAdd(&ws[W_CNT_E + etypes[b]], 1);
        atomicAdd(&ws[W_CNT_R + rtypes[b]], 1);
    }
}

// one block, 128 threads: prefix sums + chunk lists for both sides
__global__ __launch_bounds__(128) void scan_build_kernel(int* ws) {
    __shared__ int tmp[128];
    int tid = threadIdx.x;

    // ---------- entity side (128 slots, 100 real) ----------
    int c = ws[W_CNT_E + tid];
    tmp[tid] = c; __syncthreads();
    for (int off = 1; off < 128; off <<= 1) {
        int v = (tid >= off) ? tmp[tid - off] : 0; __syncthreads();
        tmp[tid] += v; __syncthreads();
    }
    int excl = tmp[tid] - c;
    ws[W_OFF_E + tid] = excl;
    ws[W_RUN_E + tid] = excl;
    int nch = (c + MTILE - 1) / MTILE;
    __syncthreads();
    tmp[tid] = nch; __syncthreads();
    for (int off = 1; off < 128; off <<= 1) {
        int v = (tid >= off) ? tmp[tid - off] : 0; __syncthreads();
        tmp[tid] += v; __syncthreads();
    }
    int cexcl = tmp[tid] - nch;
    for (int q = 0; q < nch; ++q) {
        int ci = cexcl + q;
        ws[W_CHP0_E + ci] = excl + q * MTILE;
        int rem = c - q * MTILE;
        ws[W_CHN_E + ci] = rem < MTILE ? rem : MTILE;
        ws[W_CHTT_E + ci] = tid;
    }
    if (tid == 127) ws[W_NE] = tmp[127];
    __syncthreads();

    // ---------- relation side (64 slots, 50 real) ----------
    c = (tid < 64) ? ws[W_CNT_R + tid] : 0;
    tmp[tid] = c; __syncthreads();
    for (int off = 1; off < 128; off <<= 1) {
        int v = (tid >= off) ? tmp[tid - off] : 0; __syncthreads();
        tmp[tid] += v; __syncthreads();
    }
    excl = tmp[tid] - c;
    if (tid < 64) { ws[W_OFF_R + tid] = excl; ws[W_RUN_R + tid] = excl; }
    nch = (c + MTILE - 1) / MTILE;
    __syncthreads();
    tmp[tid] = nch; __syncthreads();
    for (int off = 1; off < 128; off <<= 1) {
        int v = (tid >= off) ? tmp[tid - off] : 0; __syncthreads();
        tmp[tid] += v; __syncthreads();
    }
    cexcl = tmp[tid] - nch;
    if (tid < 64) {
        for (int q = 0; q < nch; ++q) {
            int ci = cexcl + q;
            ws[W_CHP0_R + ci] = excl + q * MTILE;
            int rem = c - q * MTILE;
            ws[W_CHN_R + ci] = rem < MTILE ? rem : MTILE;
            ws[W_CHTT_R + ci] = tid;
        }
    }
    if (tid == 127) ws[W_NR] = tmp[127];
}

__global__ __launch_bounds__(256) void scatter_kernel(
    const int* __restrict__ etypes, const int* __restrict__ rtypes,
    int* ws, int B)
{
    int* srt_e = ws + W_SRT_E;
    int* inv_e = srt_e + B;
    int* srt_r = inv_e + B;
    int* inv_r = srt_r + B;
    for (int b = blockIdx.x * blockDim.x + threadIdx.x; b < B;
         b += gridDim.x * blockDim.x) {
        int pe = atomicAdd(&ws[W_RUN_E + etypes[b]], 1);
        srt_e[pe] = b; inv_e[b] = pe;
        int pr = atomicAdd(&ws[W_RUN_R + rtypes[b]], 1);
        srt_r[pr] = b; inv_r[b] = pr;
    }
}

// C[64 x 128] = X[64 x 128] * P^T, one chunk per block.
// IS_E: X rows = eemb[h]-eemb[t], write Y[p0+m][:] = acc
// !IS_E: X rows = remb[rel],      Y[inv_e[b]][:] += acc
template<bool IS_E>
__global__ __launch_bounds__(256) void gemm_kernel(
    const int* __restrict__ heads, const int* __restrict__ tails,
    const int* __restrict__ rels,
    const float* __restrict__ eemb, const float* __restrict__ remb,
    const float* __restrict__ proj,
    const int* __restrict__ ws, int B, float* __restrict__ Y)
{
    const int nch = IS_E ? ws[W_NE] : ws[W_NR];
    if ((int)blockIdx.x >= nch) return;
    const int p0 = ws[(IS_E ? W_CHP0_E : W_CHP0_R) + blockIdx.x];
    const int nr = ws[(IS_E ? W_CHN_E  : W_CHN_R)  + blockIdx.x];
    const int tt = ws[(IS_E ? W_CHTT_E : W_CHTT_R) + blockIdx.x];
    const int* srt = ws + (IS_E ? W_SRT_E : (W_SRT_E + 2 * B));
    const int* inv_e = ws + W_SRT_E + B;
    const float* P = proj + (size_t)tt * D * D;

    __shared__ float Xs[MTILE * D];   // swizzled float4 slots, stride 128 f
    __shared__ float Ps[D * KC];      // per K-chunk, stride 32 f

    const int tid = threadIdx.x;

    // ---- stage X tile (full K), gather fused ----
    for (int idx = tid; idx < MTILE * (D / 4); idx += 256) {
        int row = idx >> 5, kq = idx & 31;
        float4 v = {0.f, 0.f, 0.f, 0.f};
        if (row < nr) {
            int b = srt[p0 + row];
            if (IS_E) {
                const float4* hp = (const float4*)(eemb + (size_t)heads[b] * D);
                const float4* tp = (const float4*)(eemb + (size_t)tails[b] * D);
                float4 hv = hp[kq], tv = tp[kq];
                v.x = hv.x - tv.x; v.y = hv.y - tv.y;
                v.z = hv.z - tv.z; v.w = hv.w - tv.w;
            } else {
                v = ((const float4*)(remb + (size_t)rels[b] * D))[kq];
            }
        }
        int slot = kq ^ (row & 7);
        *(float4*)&Xs[row * D + slot * 4] = v;
    }

    float acc[4][8];
    #pragma unroll
    for (int j = 0; j < 4; ++j)
        #pragma unroll
        for (int i = 0; i < 8; ++i) acc[j][i] = 0.f;

    const int ty = tid >> 4, tx = tid & 15;

    for (int k0 = 0; k0 < D; k0 += KC) {
        __syncthreads();
        // stage P chunk: rows n (=output col), k in [k0,k0+KC)
        for (int idx = tid; idx < D * (KC / 4); idx += 256) {
            int n = idx >> 3, kq = idx & 7;
            float4 v = *(const float4*)&P[(size_t)n * D + k0 + kq * 4];
            int slot = kq ^ ((n >> 3) & 7);
            *(float4*)&Ps[n * KC + slot * 4] = v;
        }
        __syncthreads();

        #pragma unroll
        for (int kq = 0; kq < KC / 4; ++kq) {
            float4 xv[4], pv[8];
            #pragma unroll
            for (int j = 0; j < 4; ++j) {
                int m = ty * 4 + j;
                int slot = (((k0 >> 2) + kq) ^ (m & 7)) & 31;
                xv[j] = *(const float4*)&Xs[m * D + slot * 4];
            }
            #pragma unroll
            for (int i = 0; i < 8; ++i) {
                int n = tx * 8 + i;
                int slot = kq ^ (tx & 7);
                pv[i] = *(const float4*)&Ps[n * KC + slot * 4];
            }
            #pragma unroll
            for (int j = 0; j < 4; ++j)
                #pragma unroll
                for (int i = 0; i < 8; ++i)
                    acc[j][i] += xv[j].x * pv[i].x + xv[j].y * pv[i].y
                               + xv[j].z * pv[i].z + xv[j].w * pv[i].w;
        }
    }

    // ---- epilogue ----
    #pragma unroll
    for (int j = 0; j < 4; ++j) {
        int m = ty * 4 + j;
        if (m < nr) {
            if (IS_E) {
                float* yp = Y + (size_t)(p0 + m) * D + tx * 8;
                float4 a = {acc[j][0], acc[j][1], acc[j][2], acc[j][3]};
                float4 bq = {acc[j][4], acc[j][5], acc[j][6], acc[j][7]};
                *(float4*)yp = a;
                *(float4*)(yp + 4) = bq;
            } else {
                int b = srt[p0 + m];
                float* yp = Y + (size_t)inv_e[b] * D + tx * 8;
                #pragma unroll
                for (int i = 0; i < 8; ++i) yp[i] += acc[j][i];
            }
        }
    }
}

__global__ __launch_bounds__(256) void norm_kernel(
    const int* __restrict__ ws, int B, const float* __restrict__ Y,
    float* __restrict__ out)
{
    const int* inv_e = ws + W_SRT_E + B;
    int wave = threadIdx.x >> 6, lane = threadIdx.x & 63;
    int gb = blockIdx.x * 4 + wave;
    if (gb >= B) return;
    int row = inv_e[gb];
    float2 v = ((const float2*)(Y + (size_t)row * D))[lane];
    float ss = v.x * v.x + v.y * v.y;
    #pragma unroll
    for (int off = 32; off > 0; off >>= 1)
        ss += __shfl_down(ss, off, 64);
    if (lane == 0) out[gb] = sqrtf(ss);
}

extern "C" void kernel_launch(void* const* d_in, const int* in_sizes, int n_in,
                              void* d_out, int out_size, void* d_ws, size_t ws_size,
                              hipStream_t stream) {
    const int*   heads     = (const int*)d_in[0];
    const int*   relations = (const int*)d_in[1];
    const int*   tails     = (const int*)d_in[2];
    const int*   etypes    = (const int*)d_in[3];
    const int*   rtypes    = (const int*)d_in[4];
    const float* eemb      = (const float*)d_in[5];
    const float* remb      = (const float*)d_in[6];
    const float* eproj     = (const float*)d_in[7];
    const float* rproj     = (const float*)d_in[8];
    float* out = (float*)d_out;

    const int B = in_sizes[0];   // 16384
    int* ws = (int*)d_ws;
    float* Y = (float*)d_ws + W_Y_F32;

    zero_kernel<<<1, 256, 0, stream>>>(ws);
    count_kernel<<<64, 256, 0, stream>>>(etypes, rtypes, ws, B);
    scan_build_kernel<<<1, 128, 0, stream>>>(ws);
    scatter_kernel<<<64, 256, 0, stream>>>(etypes, rtypes, ws, B);
    gemm_kernel<true ><<<512, 256, 0, stream>>>(heads, tails, relations,
                                                eemb, remb, eproj, ws, B, Y);
    gemm_kernel<false><<<512, 256, 0, stream>>>(heads, tails, relations,
                                                eemb, remb, rproj, ws, B, Y);
    norm_kernel<<<(B + 3) / 4, 256, 0, stream>>>(ws, B, Y, out);
}

// Round 4
// 426.849 us; speedup vs baseline: 1.4200x; 1.1331x over previous
//
#include <hip/hip_runtime.h>
#include <math.h>

#define D 128
#define MTILE 32
#define MAXCH 1280
#define NB 1024

// ---- workspace layout (int words) ----
#define W_NCH   0
#define W_CHP0  16                  // [MAXCH]
#define W_CHN   (16 + MAXCH)        // [MAXCH]
#define W_CHTT  (16 + 2 * MAXCH)    // [MAXCH]  (type | side<<8)
#define W_SRT   4096                // srt_e[B], inv_e[B], srt_r[B], inv_r[B]
// Ye float offset = 4096 + 4*B ; Yr = Ye + B*128

__global__ __launch_bounds__(NB) void bucket_kernel(
    const int* __restrict__ etypes, const int* __restrict__ rtypes,
    int* __restrict__ ws, int B)
{
    __shared__ int cnt_e[128], cnt_r[64], off_e[128], off_r[64], tmp[128];
    __shared__ int s_nche;
    const int tid = threadIdx.x;

    if (tid < 128) cnt_e[tid] = 0;
    if (tid < 64)  cnt_r[tid] = 0;
    __syncthreads();
    for (int b = tid; b < B; b += NB) {
        atomicAdd(&cnt_e[etypes[b]], 1);
        atomicAdd(&cnt_r[rtypes[b]], 1);
    }
    __syncthreads();

    // ---------- entity side ----------
    int c = (tid < 128) ? cnt_e[tid] : 0;
    if (tid < 128) tmp[tid] = c;
    __syncthreads();
    for (int off = 1; off < 128; off <<= 1) {
        int v = (tid < 128 && tid >= off) ? tmp[tid - off] : 0;
        __syncthreads();
        if (tid < 128) tmp[tid] += v;
        __syncthreads();
    }
    int excl = (tid < 128) ? (tmp[tid] - c) : 0;
    if (tid < 128) off_e[tid] = excl;
    int nch = (tid < 128) ? ((c + MTILE - 1) / MTILE) : 0;
    __syncthreads();
    if (tid < 128) tmp[tid] = nch;
    __syncthreads();
    for (int off = 1; off < 128; off <<= 1) {
        int v = (tid < 128 && tid >= off) ? tmp[tid - off] : 0;
        __syncthreads();
        if (tid < 128) tmp[tid] += v;
        __syncthreads();
    }
    if (tid < 128) {
        int cexcl = tmp[tid] - nch;
        for (int q = 0; q < nch; ++q) {
            int ci = cexcl + q;
            ws[W_CHP0 + ci] = excl + q * MTILE;
            int rem = c - q * MTILE;
            ws[W_CHN + ci] = rem < MTILE ? rem : MTILE;
            ws[W_CHTT + ci] = tid;            // side 0
        }
    }
    if (tid == 127) s_nche = tmp[127];
    __syncthreads();
    const int NEch = s_nche;

    // ---------- relation side ----------
    c = (tid < 64) ? cnt_r[tid] : 0;
    if (tid < 128) tmp[tid] = c;
    __syncthreads();
    for (int off = 1; off < 128; off <<= 1) {
        int v = (tid < 128 && tid >= off) ? tmp[tid - off] : 0;
        __syncthreads();
        if (tid < 128) tmp[tid] += v;
        __syncthreads();
    }
    excl = (tid < 128) ? (tmp[tid] - c) : 0;
    if (tid < 64) off_r[tid] = excl;
    nch = (tid < 64) ? ((c + MTILE - 1) / MTILE) : 0;
    __syncthreads();
    if (tid < 128) tmp[tid] = nch;
    __syncthreads();
    for (int off = 1; off < 128; off <<= 1) {
        int v = (tid < 128 && tid >= off) ? tmp[tid - off] : 0;
        __syncthreads();
        if (tid < 128) tmp[tid] += v;
        __syncthreads();
    }
    if (tid < 64) {
        int cexcl = tmp[tid] - nch;
        for (int q = 0; q < nch; ++q) {
            int ci = NEch + cexcl + q;
            ws[W_CHP0 + ci] = excl + q * MTILE;
            int rem = c - q * MTILE;
            ws[W_CHN + ci] = rem < MTILE ? rem : MTILE;
            ws[W_CHTT + ci] = tid | 256;      // side 1
        }
    }
    if (tid == 127) ws[W_NCH] = NEch + tmp[127];
    __syncthreads();

    // ---------- scatter ----------
    int* srt_e = ws + W_SRT;
    int* inv_e = srt_e + B;
    int* srt_r = inv_e + B;
    int* inv_r = srt_r + B;
    for (int b = tid; b < B; b += NB) {
        int pe = atomicAdd(&off_e[etypes[b]], 1);
        srt_e[pe] = b; inv_e[b] = pe;
        int pr = atomicAdd(&off_r[rtypes[b]], 1);
        srt_r[pr] = b; inv_r[b] = pr;
    }
}

// One chunk (32 rows x full N=128) per block. side 0: X=h-t, out->Ye.
// side 1: X=remb[rel], out->Yr. Pure "=" stores, no ordering needed.
__global__ __launch_bounds__(256) void gemm_fused(
    const int* __restrict__ heads, const int* __restrict__ tails,
    const int* __restrict__ rels,
    const float* __restrict__ eemb, const float* __restrict__ remb,
    const float* __restrict__ eproj, const float* __restrict__ rproj,
    const int* __restrict__ ws, int B,
    float* __restrict__ Ye, float* __restrict__ Yr)
{
    const int nch = ws[W_NCH];
    if ((int)blockIdx.x >= nch) return;
    const int p0  = ws[W_CHP0 + blockIdx.x];
    const int nr  = ws[W_CHN  + blockIdx.x];
    const int tts = ws[W_CHTT + blockIdx.x];
    const int side = tts >> 8, tt = tts & 255;
    const int* srt = ws + W_SRT + (side ? 2 * B : 0);
    const float* P = (side ? rproj : eproj) + (size_t)tt * D * D;
    float* Y = side ? Yr : Ye;

    __shared__ float Xs[MTILE * 132];   // stride 132 floats (pad 4)
    __shared__ float Ps[D * 36];        // stride 36 floats (pad 4)

    const int tid = threadIdx.x;

    // stage X tile (full K=128), gather fused
    for (int idx = tid; idx < MTILE * 32; idx += 256) {
        int row = idx >> 5, kq = idx & 31;
        float4 v = {0.f, 0.f, 0.f, 0.f};
        if (row < nr) {
            int b = srt[p0 + row];
            if (side == 0) {
                float4 hv = ((const float4*)(eemb + (size_t)heads[b] * D))[kq];
                float4 tv = ((const float4*)(eemb + (size_t)tails[b] * D))[kq];
                v.x = hv.x - tv.x; v.y = hv.y - tv.y;
                v.z = hv.z - tv.z; v.w = hv.w - tv.w;
            } else {
                v = ((const float4*)(remb + (size_t)rels[b] * D))[kq];
            }
        }
        *(float4*)&Xs[row * 132 + kq * 4] = v;
    }

    float acc[2][8];
    #pragma unroll
    for (int j = 0; j < 2; ++j)
        #pragma unroll
        for (int i = 0; i < 8; ++i) acc[j][i] = 0.f;

    const int ty = tid >> 4, tx = tid & 15;   // rows ty*2+{0,1}, cols i*16+tx

    for (int k0 = 0; k0 < 32; k0 += 8) {      // k in float4-quads
        __syncthreads();
        for (int idx = tid; idx < 1024; idx += 256) {
            int n = idx >> 3, kq = idx & 7;
            float4 v = *(const float4*)&P[(size_t)n * D + (k0 + kq) * 4];
            *(float4*)&Ps[n * 36 + kq * 4] = v;
        }
        __syncthreads();

        #pragma unroll
        for (int kq = 0; kq < 8; ++kq) {
            float4 xv[2], pv[8];
            #pragma unroll
            for (int j = 0; j < 2; ++j)
                xv[j] = *(const float4*)&Xs[(ty * 2 + j) * 132 + (k0 + kq) * 4];
            #pragma unroll
            for (int i = 0; i < 8; ++i)
                pv[i] = *(const float4*)&Ps[(i * 16 + tx) * 36 + kq * 4];
            #pragma unroll
            for (int j = 0; j < 2; ++j)
                #pragma unroll
                for (int i = 0; i < 8; ++i)
                    acc[j][i] += xv[j].x * pv[i].x + xv[j].y * pv[i].y
                               + xv[j].z * pv[i].z + xv[j].w * pv[i].w;
        }
    }

    #pragma unroll
    for (int j = 0; j < 2; ++j) {
        int m = ty * 2 + j;
        if (m < nr) {
            float* yp = Y + (size_t)(p0 + m) * D + tx;
            #pragma unroll
            for (int i = 0; i < 8; ++i) yp[i * 16] = acc[j][i];
        }
    }
}

__global__ __launch_bounds__(256) void norm_kernel(
    const int* __restrict__ ws, int B,
    const float* __restrict__ Ye, const float* __restrict__ Yr,
    float* __restrict__ out)
{
    int wave = threadIdx.x >> 6, lane = threadIdx.x & 63;
    int gb = blockIdx.x * 4 + wave;
    if (gb >= B) return;
    int re = ws[W_SRT + B + gb];          // inv_e[gb]
    int rr = ws[W_SRT + 3 * B + gb];      // inv_r[gb]
    float2 a = ((const float2*)(Ye + (size_t)re * D))[lane];
    float2 c = ((const float2*)(Yr + (size_t)rr * D))[lane];
    float x0 = a.x + c.x, x1 = a.y + c.y;
    float ss = x0 * x0 + x1 * x1;
    #pragma unroll
    for (int off = 32; off > 0; off >>= 1)
        ss += __shfl_down(ss, off, 64);
    if (lane == 0) out[gb] = sqrtf(ss);
}

extern "C" void kernel_launch(void* const* d_in, const int* in_sizes, int n_in,
                              void* d_out, int out_size, void* d_ws, size_t ws_size,
                              hipStream_t stream) {
    const int*   heads     = (const int*)d_in[0];
    const int*   relations = (const int*)d_in[1];
    const int*   tails     = (const int*)d_in[2];
    const int*   etypes    = (const int*)d_in[3];
    const int*   rtypes    = (const int*)d_in[4];
    const float* eemb      = (const float*)d_in[5];
    const float* remb      = (const float*)d_in[6];
    const float* eproj     = (const float*)d_in[7];
    const float* rproj     = (const float*)d_in[8];
    float* out = (float*)d_out;

    const int B = in_sizes[0];   // 16384
    int* ws = (int*)d_ws;
    float* Ye = (float*)d_ws + (W_SRT + 4 * B);
    float* Yr = Ye + (size_t)B * D;

    bucket_kernel<<<1, NB, 0, stream>>>(etypes, rtypes, ws, B);
    gemm_fused<<<MAXCH, 256, 0, stream>>>(heads, tails, relations,
                                          eemb, remb, eproj, rproj, ws, B, Ye, Yr);
    norm_kernel<<<(B + 3) / 4, 256, 0, stream>>>(ws, B, Ye, Yr, out);
}